// Round 1
// baseline (433.847 us; speedup 1.0000x reference)
//
#include <hip/hip_runtime.h>

#define NB 8
#define NC 64
#define NH 256
#define NW 512
#define ND 16
#define HW (NH * NW)
#define EPSV 1e-6f

#define TH 16
#define TW 16
#define EH (TH + 2)
#define EW (TW + 2)
#define NEXTP (EH * EW)   // 324 extended pixels
#define PSTR 17           // padded per-pixel LDS stride (floats), odd -> conflict-free

__global__ __launch_bounds__(256, 2)
void na2d_fused_kernel(const float* __restrict__ x,
                       const float* __restrict__ wqkv,
                       const float* __restrict__ wout,
                       float* __restrict__ y)
{
    __shared__ float s_k[NEXTP * PSTR];   // 22 KB
    __shared__ float s_v[NEXTP * PSTR];   // 22 KB

    const int t  = threadIdx.x;
    const int w0 = blockIdx.x * TW;
    const int h0 = blockIdx.y * TH;
    const int b  = blockIdx.z;

    const float* __restrict__ xb = x + (size_t)b * NC * HW;

    // ---- Phase A: phi(k), v for all extended (halo) pixels -> LDS ----
    for (int p = t; p < NEXTP; p += 256) {
        const int ey = p / EW;
        const int ex = p - ey * EW;
        const int hh = h0 + ey - 1;
        const int ww = w0 + ex - 1;
        float* sk = &s_k[p * PSTR];
        float* sv = &s_v[p * PSTR];
        if ((unsigned)hh < NH && (unsigned)ww < NW) {
            float acc[32];
            #pragma unroll
            for (int o = 0; o < 32; ++o) acc[o] = 0.f;
            const float* xp = xb + hh * NW + ww;
            for (int c0 = 0; c0 < NC; c0 += 8) {
                float xv[8];
                #pragma unroll
                for (int j = 0; j < 8; ++j)
                    xv[j] = xp[(size_t)(c0 + j) * HW];
                #pragma unroll
                for (int j = 0; j < 8; ++j) {
                    #pragma unroll
                    for (int o = 0; o < 32; ++o)
                        acc[o] = fmaf(wqkv[(ND + o) * NC + c0 + j], xv[j], acc[o]);
                }
            }
            #pragma unroll
            for (int o = 0; o < 16; ++o) {          // k rows 16..31, phi = elu+1
                const float kv = acc[o];
                sk[o] = kv > 0.f ? kv + 1.f : __expf(kv);
            }
            #pragma unroll
            for (int o = 0; o < 16; ++o) sv[o] = acc[16 + o];  // v rows 32..47
        } else {
            // zero-pad AFTER phi (matches reference _neighborhoods semantics)
            #pragma unroll
            for (int o = 0; o < 16; ++o) { sk[o] = 0.f; sv[o] = 0.f; }
        }
    }

    // ---- Phase B: phi(q) for own interior pixel (registers) ----
    const int py = t >> 4;
    const int px = t & 15;
    const int hh = h0 + py;
    const int ww = w0 + px;
    float q[ND];
    {
        float acc[ND];
        #pragma unroll
        for (int o = 0; o < ND; ++o) acc[o] = 0.f;
        const float* xp = xb + hh * NW + ww;
        for (int c0 = 0; c0 < NC; c0 += 8) {
            float xv[8];
            #pragma unroll
            for (int j = 0; j < 8; ++j)
                xv[j] = xp[(size_t)(c0 + j) * HW];
            #pragma unroll
            for (int j = 0; j < 8; ++j) {
                #pragma unroll
                for (int o = 0; o < ND; ++o)
                    acc[o] = fmaf(wqkv[o * NC + c0 + j], xv[j], acc[o]);
            }
        }
        #pragma unroll
        for (int o = 0; o < ND; ++o)
            q[o] = acc[o] > 0.f ? acc[o] + 1.f : __expf(acc[o]);
    }

    __syncthreads();

    // ---- Phase C: scores -> weights -> weighted V -> output projection ----
    float sc[9];
    float ssum = 0.f;
    #pragma unroll
    for (int n = 0; n < 9; ++n) {
        const int np = (py + n / 3) * EW + (px + n % 3);
        const float* sk = &s_k[np * PSTR];
        float s = 0.f;
        #pragma unroll
        for (int d = 0; d < ND; ++d) s = fmaf(q[d], sk[d], s);
        sc[n] = s;
        ssum += s;
    }
    const float inv = 1.f / (ssum + EPSV);

    float ov[ND];
    #pragma unroll
    for (int d = 0; d < ND; ++d) ov[d] = 0.f;
    #pragma unroll
    for (int n = 0; n < 9; ++n) {
        const int np = (py + n / 3) * EW + (px + n % 3);
        const float* sv = &s_v[np * PSTR];
        const float wn = sc[n] * inv;
        #pragma unroll
        for (int d = 0; d < ND; ++d) ov[d] = fmaf(wn, sv[d], ov[d]);
    }

    float* yp = y + (size_t)b * NC * HW + hh * NW + ww;
    #pragma unroll 8
    for (int o = 0; o < NC; ++o) {
        float acc = 0.f;
        #pragma unroll
        for (int d = 0; d < ND; ++d)
            acc = fmaf(wout[o * ND + d], ov[d], acc);
        yp[(size_t)o * HW] = acc;
    }
}

extern "C" void kernel_launch(void* const* d_in, const int* in_sizes, int n_in,
                              void* d_out, int out_size, void* d_ws, size_t ws_size,
                              hipStream_t stream)
{
    const float* x    = (const float*)d_in[0];
    const float* wqkv = (const float*)d_in[1];
    const float* wout = (const float*)d_in[2];
    float* y = (float*)d_out;

    dim3 grid(NW / TW, NH / TH, NB);
    na2d_fused_kernel<<<grid, 256, 0, stream>>>(x, wqkv, wout, y);
}

// Round 2
// 404.390 us; speedup vs baseline: 1.0728x; 1.0728x over previous
//
#include <hip/hip_runtime.h>
#include <hip/hip_fp16.h>

#define NB 8
#define NC 64
#define NH 256
#define NW 512
#define ND 16
#define HW (NH * NW)          // 131072 = 2^17
#define EPSV 1e-6f
#define NQKV 48               // q(16) + k(16) + v(16) per pixel

// ---------------------------------------------------------------------------
// K1: qkv projection + phi, write 48 fp16 per pixel (pixel-major records).
// 1 thread per pixel; x loads fully coalesced (lane = consecutive pixel).
// ---------------------------------------------------------------------------
__global__ __launch_bounds__(256)
void qkv_proj_kernel(const float* __restrict__ x,
                     const float* __restrict__ wqkv,
                     __half* __restrict__ qkv)
{
    const int g = blockIdx.x * 256 + threadIdx.x;  // global pixel index
    const int b = g >> 17;                          // / HW
    const int p = g & (HW - 1);                     // % HW
    const float* xp = x + (size_t)b * NC * HW + p;

    float acc[NQKV];
    #pragma unroll
    for (int o = 0; o < NQKV; ++o) acc[o] = 0.f;

    for (int c0 = 0; c0 < NC; c0 += 8) {
        float xv[8];
        #pragma unroll
        for (int j = 0; j < 8; ++j)
            xv[j] = xp[(size_t)(c0 + j) * HW];
        #pragma unroll
        for (int j = 0; j < 8; ++j) {
            #pragma unroll
            for (int o = 0; o < NQKV; ++o)
                acc[o] = fmaf(wqkv[o * NC + c0 + j], xv[j], acc[o]);
        }
    }

    // phi = elu + 1 on q (0..15) and k (16..31); v (32..47) raw
    #pragma unroll
    for (int o = 0; o < 32; ++o)
        acc[o] = acc[o] > 0.f ? acc[o] + 1.f : __expf(acc[o]);

    unsigned int u[24];
    #pragma unroll
    for (int i = 0; i < 24; ++i) {
        __half2 h = __floats2half2_rn(acc[2 * i], acc[2 * i + 1]);
        u[i] = *reinterpret_cast<unsigned int*>(&h);
    }
    uint4* dst = reinterpret_cast<uint4*>(qkv + (size_t)g * NQKV);
    #pragma unroll
    for (int i = 0; i < 6; ++i)
        dst[i] = make_uint4(u[4 * i], u[4 * i + 1], u[4 * i + 2], u[4 * i + 3]);
}

// ---------------------------------------------------------------------------
// K2: neighborhood attention + output projection. No LDS: 9 neighbor records
// read directly (L1-resident per block; halo reuse via L2/L3).
// ---------------------------------------------------------------------------
__device__ __forceinline__ void unpack8(const uint4 u, float* f)
{
    *reinterpret_cast<float2*>(f + 0) = __half22float2(*reinterpret_cast<const __half2*>(&u.x));
    *reinterpret_cast<float2*>(f + 2) = __half22float2(*reinterpret_cast<const __half2*>(&u.y));
    *reinterpret_cast<float2*>(f + 4) = __half22float2(*reinterpret_cast<const __half2*>(&u.z));
    *reinterpret_cast<float2*>(f + 6) = __half22float2(*reinterpret_cast<const __half2*>(&u.w));
}

__global__ __launch_bounds__(256)
void attn_out_kernel(const __half* __restrict__ qkv,
                     const float* __restrict__ wout,
                     float* __restrict__ y)
{
    const int t  = threadIdx.x;
    const int px = t & 15, py = t >> 4;
    const int w  = blockIdx.x * 16 + px;
    const int h  = blockIdx.y * 16 + py;
    const int b  = blockIdx.z;

    const __half* base = qkv + (size_t)b * HW * NQKV;

    // own phi(q)
    float q[ND];
    {
        const uint4* qp = reinterpret_cast<const uint4*>(base + (size_t)(h * NW + w) * NQKV);
        unpack8(qp[0], q);
        unpack8(qp[1], q + 8);
    }

    // pass 1: scores over 9 neighbors (phi(k) at record offset 16)
    float sc[9];
    float ssum = 0.f;
    #pragma unroll
    for (int n = 0; n < 9; ++n) {
        const int hh = h - 1 + n / 3;
        const int ww = w - 1 + n % 3;
        float s = 0.f;
        if ((unsigned)hh < NH && (unsigned)ww < NW) {
            const uint4* kp = reinterpret_cast<const uint4*>(base + (size_t)(hh * NW + ww) * NQKV + 16);
            float kf[16];
            unpack8(kp[0], kf);
            unpack8(kp[1], kf + 8);
            #pragma unroll
            for (int d = 0; d < ND; ++d) s = fmaf(q[d], kf[d], s);
        }
        sc[n] = s;
        ssum += s;
    }
    const float inv = 1.f / (ssum + EPSV);

    // pass 2: weighted V accumulation (v at record offset 32; L1 hits)
    float ov[ND];
    #pragma unroll
    for (int d = 0; d < ND; ++d) ov[d] = 0.f;
    #pragma unroll
    for (int n = 0; n < 9; ++n) {
        const int hh = h - 1 + n / 3;
        const int ww = w - 1 + n % 3;
        if ((unsigned)hh < NH && (unsigned)ww < NW) {
            const float wn = sc[n] * inv;
            const uint4* vp = reinterpret_cast<const uint4*>(base + (size_t)(hh * NW + ww) * NQKV + 32);
            float vf[16];
            unpack8(vp[0], vf);
            unpack8(vp[1], vf + 8);
            #pragma unroll
            for (int d = 0; d < ND; ++d) ov[d] = fmaf(wn, vf[d], ov[d]);
        }
    }

    // output projection 16 -> 64
    float* yp = y + (size_t)b * NC * HW + h * NW + w;
    #pragma unroll 8
    for (int o = 0; o < NC; ++o) {
        float a = 0.f;
        #pragma unroll
        for (int d = 0; d < ND; ++d)
            a = fmaf(wout[o * ND + d], ov[d], a);
        yp[(size_t)o * HW] = a;
    }
}

// ---------------------------------------------------------------------------
// Fallback: round-1 fused kernel (used only if ws_size is too small).
// ---------------------------------------------------------------------------
#define TH 16
#define TW 16
#define EH (TH + 2)
#define EW (TW + 2)
#define NEXTP (EH * EW)
#define PSTR 17

__global__ __launch_bounds__(256, 2)
void na2d_fused_kernel(const float* __restrict__ x,
                       const float* __restrict__ wqkv,
                       const float* __restrict__ wout,
                       float* __restrict__ y)
{
    __shared__ float s_k[NEXTP * PSTR];
    __shared__ float s_v[NEXTP * PSTR];

    const int t  = threadIdx.x;
    const int w0 = blockIdx.x * TW;
    const int h0 = blockIdx.y * TH;
    const int b  = blockIdx.z;

    const float* __restrict__ xb = x + (size_t)b * NC * HW;

    for (int p = t; p < NEXTP; p += 256) {
        const int ey = p / EW;
        const int ex = p - ey * EW;
        const int hh = h0 + ey - 1;
        const int ww = w0 + ex - 1;
        float* sk = &s_k[p * PSTR];
        float* sv = &s_v[p * PSTR];
        if ((unsigned)hh < NH && (unsigned)ww < NW) {
            float acc[32];
            #pragma unroll
            for (int o = 0; o < 32; ++o) acc[o] = 0.f;
            const float* xp = xb + hh * NW + ww;
            for (int c0 = 0; c0 < NC; c0 += 8) {
                float xv[8];
                #pragma unroll
                for (int j = 0; j < 8; ++j)
                    xv[j] = xp[(size_t)(c0 + j) * HW];
                #pragma unroll
                for (int j = 0; j < 8; ++j) {
                    #pragma unroll
                    for (int o = 0; o < 32; ++o)
                        acc[o] = fmaf(wqkv[(ND + o) * NC + c0 + j], xv[j], acc[o]);
                }
            }
            #pragma unroll
            for (int o = 0; o < 16; ++o) {
                const float kv = acc[o];
                sk[o] = kv > 0.f ? kv + 1.f : __expf(kv);
            }
            #pragma unroll
            for (int o = 0; o < 16; ++o) sv[o] = acc[16 + o];
        } else {
            #pragma unroll
            for (int o = 0; o < 16; ++o) { sk[o] = 0.f; sv[o] = 0.f; }
        }
    }

    const int py = t >> 4;
    const int px = t & 15;
    const int hh = h0 + py;
    const int ww = w0 + px;
    float q[ND];
    {
        float acc[ND];
        #pragma unroll
        for (int o = 0; o < ND; ++o) acc[o] = 0.f;
        const float* xp = xb + hh * NW + ww;
        for (int c0 = 0; c0 < NC; c0 += 8) {
            float xv[8];
            #pragma unroll
            for (int j = 0; j < 8; ++j)
                xv[j] = xp[(size_t)(c0 + j) * HW];
            #pragma unroll
            for (int j = 0; j < 8; ++j) {
                #pragma unroll
                for (int o = 0; o < ND; ++o)
                    acc[o] = fmaf(wqkv[o * NC + c0 + j], xv[j], acc[o]);
            }
        }
        #pragma unroll
        for (int o = 0; o < ND; ++o)
            q[o] = acc[o] > 0.f ? acc[o] + 1.f : __expf(acc[o]);
    }

    __syncthreads();

    float sc[9];
    float ssum = 0.f;
    #pragma unroll
    for (int n = 0; n < 9; ++n) {
        const int np = (py + n / 3) * EW + (px + n % 3);
        const float* sk = &s_k[np * PSTR];
        float s = 0.f;
        #pragma unroll
        for (int d = 0; d < ND; ++d) s = fmaf(q[d], sk[d], s);
        sc[n] = s;
        ssum += s;
    }
    const float inv = 1.f / (ssum + EPSV);

    float ov[ND];
    #pragma unroll
    for (int d = 0; d < ND; ++d) ov[d] = 0.f;
    #pragma unroll
    for (int n = 0; n < 9; ++n) {
        const int np = (py + n / 3) * EW + (px + n % 3);
        const float* sv = &s_v[np * PSTR];
        const float wn = sc[n] * inv;
        #pragma unroll
        for (int d = 0; d < ND; ++d) ov[d] = fmaf(wn, sv[d], ov[d]);
    }

    float* yp = y + (size_t)b * NC * HW + hh * NW + ww;
    #pragma unroll 8
    for (int o = 0; o < NC; ++o) {
        float acc = 0.f;
        #pragma unroll
        for (int d = 0; d < ND; ++d)
            acc = fmaf(wout[o * ND + d], ov[d], acc);
        yp[(size_t)o * HW] = acc;
    }
}

extern "C" void kernel_launch(void* const* d_in, const int* in_sizes, int n_in,
                              void* d_out, int out_size, void* d_ws, size_t ws_size,
                              hipStream_t stream)
{
    const float* x    = (const float*)d_in[0];
    const float* wqkv = (const float*)d_in[1];
    const float* wout = (const float*)d_in[2];
    float* y = (float*)d_out;

    const size_t need = (size_t)NB * HW * NQKV * sizeof(__half);  // ~100.7 MB
    if (ws_size >= need) {
        __half* qkv = (__half*)d_ws;
        const int npix = NB * HW;
        qkv_proj_kernel<<<npix / 256, 256, 0, stream>>>(x, wqkv, qkv);
        dim3 grid2(NW / 16, NH / 16, NB);
        attn_out_kernel<<<grid2, 256, 0, stream>>>(qkv, wout, y);
    } else {
        dim3 grid(NW / TW, NH / TH, NB);
        na2d_fused_kernel<<<grid, 256, 0, stream>>>(x, wqkv, wout, y);
    }
}

// Round 3
// 235.975 us; speedup vs baseline: 1.8385x; 1.7137x over previous
//
#include <hip/hip_runtime.h>
#include <hip/hip_fp16.h>

#define NB 8
#define NC 64
#define NH 256
#define NW 512
#define ND 16
#define HW (NH * NW)          // 131072 = 2^17
#define EPSV 1e-6f
#define NQKV 48               // q(16) + k(16) + v(16) fp16 per pixel record
#define RS 56                 // padded LDS record stride (fp16 elements)

typedef __attribute__((ext_vector_type(8))) short bf16x8;
typedef __attribute__((ext_vector_type(4))) float f32x4;

__device__ __forceinline__ short bf_hi(float f) {
    return (short)(__float_as_uint(f) >> 16);           // truncated bf16
}
__device__ __forceinline__ float hi_part(float f) {
    return __uint_as_float(__float_as_uint(f) & 0xFFFF0000u);
}

// ---------------------------------------------------------------------------
// K1: qkv projection via MFMA (bf16 3-term split = fp32-accurate), phi, and
// fp16 record write. Wave computes 48 channels x 64 pixels.
// ---------------------------------------------------------------------------
__global__ __launch_bounds__(256, 2)
void qkv_mfma_kernel(const float* __restrict__ x,
                     const float* __restrict__ wqkv,
                     __half* __restrict__ qkv)
{
    __shared__ __half s_t[256 * RS];   // 28672 B transpose buffer

    const int t    = threadIdx.x;
    const int wid  = t >> 6;
    const int lane = t & 63;
    const int lg   = lane >> 4;   // lane group 0..3
    const int lr   = lane & 15;   // row/col within fragment

    const long long gp0 = (long long)blockIdx.x * 256 + wid * 64; // wave's first pixel
    const int b  = (int)(gp0 >> 17);
    const int p0 = (int)(gp0 & (HW - 1));
    const float* __restrict__ xb = x + (size_t)b * NC * HW;

    // ---- A fragments: W[row=o][k=c], hi/lo split ----
    bf16x8 a_hi[3][2], a_lo[3][2];
    #pragma unroll
    for (int og = 0; og < 3; ++og) {
        const int row = og * 16 + lr;
        #pragma unroll
        for (int ks = 0; ks < 2; ++ks) {
            #pragma unroll
            for (int i = 0; i < 8; ++i) {
                const int c = ks * 32 + lg * 8 + i;
                const float wv = wqkv[row * NC + c];
                a_hi[og][ks][i] = bf_hi(wv);
                a_lo[og][ks][i] = bf_hi(wv - hi_part(wv));
            }
        }
    }

    f32x4 acc[3][4];
    #pragma unroll
    for (int og = 0; og < 3; ++og)
        #pragma unroll
        for (int pg = 0; pg < 4; ++pg)
            acc[og][pg] = (f32x4)(0.f);

    #pragma unroll
    for (int pg = 0; pg < 4; ++pg) {
        const int p = p0 + pg * 16 + lr;
        bf16x8 b_hi[2], b_lo[2];
        #pragma unroll
        for (int ks = 0; ks < 2; ++ks) {
            #pragma unroll
            for (int i = 0; i < 8; ++i) {
                const int c = ks * 32 + lg * 8 + i;
                const float xv = xb[(size_t)c * HW + p];
                b_hi[ks][i] = bf_hi(xv);
                b_lo[ks][i] = bf_hi(xv - hi_part(xv));
            }
        }
        #pragma unroll
        for (int og = 0; og < 3; ++og) {
            #pragma unroll
            for (int ks = 0; ks < 2; ++ks) {
                acc[og][pg] = __builtin_amdgcn_mfma_f32_16x16x32_bf16(a_hi[og][ks], b_hi[ks], acc[og][pg], 0, 0, 0);
                acc[og][pg] = __builtin_amdgcn_mfma_f32_16x16x32_bf16(a_lo[og][ks], b_hi[ks], acc[og][pg], 0, 0, 0);
                acc[og][pg] = __builtin_amdgcn_mfma_f32_16x16x32_bf16(a_hi[og][ks], b_lo[ks], acc[og][pg], 0, 0, 0);
            }
        }
    }

    // phi = elu+1 on q (rows 0..15) and k (rows 16..31); v raw.
    // D layout: row = og*16 + lg*4 + i (channel), col = lr (pixel).
    #pragma unroll
    for (int og = 0; og < 2; ++og)       // q and k groups only
        #pragma unroll
        for (int pg = 0; pg < 4; ++pg)
            #pragma unroll
            for (int i = 0; i < 4; ++i) {
                const float v = acc[og][pg][i];
                acc[og][pg][i] = v > 0.f ? v + 1.f : __expf(v);
            }

    // transpose via LDS -> contiguous 96 B records
    #pragma unroll
    for (int og = 0; og < 3; ++og)
        #pragma unroll
        for (int pg = 0; pg < 4; ++pg) {
            const int px = wid * 64 + pg * 16 + lr;     // pixel in block 0..255
            const int ch = og * 16 + lg * 4;
            __half2* d = reinterpret_cast<__half2*>(&s_t[px * RS + ch]);
            d[0] = __floats2half2_rn(acc[og][pg][0], acc[og][pg][1]);
            d[1] = __floats2half2_rn(acc[og][pg][2], acc[og][pg][3]);
        }
    __syncthreads();

    uint4* dst = reinterpret_cast<uint4*>(qkv + ((size_t)blockIdx.x * 256 + t) * NQKV);
    const uint4* src = reinterpret_cast<const uint4*>(&s_t[t * RS]);
    #pragma unroll
    for (int i = 0; i < 6; ++i) dst[i] = src[i];
}

// ---------------------------------------------------------------------------
// K2: neighborhood attention + output projection, LDS-staged tile.
// ---------------------------------------------------------------------------
__device__ __forceinline__ void unpack8(const uint4 u, float* f)
{
    *reinterpret_cast<float2*>(f + 0) = __half22float2(*reinterpret_cast<const __half2*>(&u.x));
    *reinterpret_cast<float2*>(f + 2) = __half22float2(*reinterpret_cast<const __half2*>(&u.y));
    *reinterpret_cast<float2*>(f + 4) = __half22float2(*reinterpret_cast<const __half2*>(&u.z));
    *reinterpret_cast<float2*>(f + 6) = __half22float2(*reinterpret_cast<const __half2*>(&u.w));
}

__global__ __launch_bounds__(256)
void attn_out_kernel(const __half* __restrict__ qkv,
                     const float* __restrict__ wout,
                     float* __restrict__ y)
{
    __shared__ __half s[324 * RS];   // 18x18 records, 36288 B

    const int t  = threadIdx.x;
    const int w0 = blockIdx.x * 16;
    const int h0 = blockIdx.y * 16;
    const int b  = blockIdx.z;
    const __half* __restrict__ base = qkv + (size_t)b * HW * NQKV;

    // stage 324 records x 96 B (zero-fill out-of-image => zero-pad after phi)
    for (int i = t; i < 324 * 6; i += 256) {
        const int r  = i / 6;
        const int j  = i - r * 6;
        const int ey = r / 18;
        const int ex = r - ey * 18;
        const int hh = h0 + ey - 1;
        const int ww = w0 + ex - 1;
        uint4 val = make_uint4(0u, 0u, 0u, 0u);
        if ((unsigned)hh < NH && (unsigned)ww < NW)
            val = reinterpret_cast<const uint4*>(base + (size_t)(hh * NW + ww) * NQKV)[j];
        *reinterpret_cast<uint4*>(&s[r * RS + j * 8]) = val;
    }
    __syncthreads();

    const int px = t & 15, py = t >> 4;
    const int rbase = (py + 1) * 18 + (px + 1);

    // own phi(q)
    float q[ND];
    {
        const uint4* qp = reinterpret_cast<const uint4*>(&s[rbase * RS]);
        unpack8(qp[0], q);
        unpack8(qp[1], q + 8);
    }

    // scores over 9 neighbors (k at fp16 offset 16)
    float sc[9];
    float ssum = 0.f;
    #pragma unroll
    for (int n = 0; n < 9; ++n) {
        const int r = (py + n / 3) * 18 + (px + n % 3);
        const uint4* kp = reinterpret_cast<const uint4*>(&s[r * RS + 16]);
        float kf[ND];
        unpack8(kp[0], kf);
        unpack8(kp[1], kf + 8);
        float sv = 0.f;
        #pragma unroll
        for (int d = 0; d < ND; ++d) sv = fmaf(q[d], kf[d], sv);
        sc[n] = sv;
        ssum += sv;
    }
    const float inv = 1.f / (ssum + EPSV);

    // weighted V (v at fp16 offset 32)
    float ov[ND];
    #pragma unroll
    for (int d = 0; d < ND; ++d) ov[d] = 0.f;
    #pragma unroll
    for (int n = 0; n < 9; ++n) {
        const int r = (py + n / 3) * 18 + (px + n % 3);
        const uint4* vp = reinterpret_cast<const uint4*>(&s[r * RS + 32]);
        float vf[ND];
        unpack8(vp[0], vf);
        unpack8(vp[1], vf + 8);
        const float wn = sc[n] * inv;
        #pragma unroll
        for (int d = 0; d < ND; ++d) ov[d] = fmaf(wn, vf[d], ov[d]);
    }

    // output projection 16 -> 64
    const int h = h0 + py, w = w0 + px;
    float* yp = y + (size_t)b * NC * HW + h * NW + w;
    #pragma unroll 8
    for (int o = 0; o < NC; ++o) {
        float a = 0.f;
        #pragma unroll
        for (int d = 0; d < ND; ++d)
            a = fmaf(wout[o * ND + d], ov[d], a);
        yp[(size_t)o * HW] = a;
    }
}

// ---------------------------------------------------------------------------
// Fallback (only if ws_size too small): round-1 fully fused kernel.
// ---------------------------------------------------------------------------
#define TH 16
#define TW 16
#define EH (TH + 2)
#define EW (TW + 2)
#define NEXTP (EH * EW)
#define PSTR 17

__global__ __launch_bounds__(256, 2)
void na2d_fused_kernel(const float* __restrict__ x,
                       const float* __restrict__ wqkv,
                       const float* __restrict__ wout,
                       float* __restrict__ y)
{
    __shared__ float s_k[NEXTP * PSTR];
    __shared__ float s_v[NEXTP * PSTR];

    const int t  = threadIdx.x;
    const int w0 = blockIdx.x * TW;
    const int h0 = blockIdx.y * TH;
    const int b  = blockIdx.z;

    const float* __restrict__ xb = x + (size_t)b * NC * HW;

    for (int p = t; p < NEXTP; p += 256) {
        const int ey = p / EW;
        const int ex = p - ey * EW;
        const int hh = h0 + ey - 1;
        const int ww = w0 + ex - 1;
        float* sk = &s_k[p * PSTR];
        float* sv = &s_v[p * PSTR];
        if ((unsigned)hh < NH && (unsigned)ww < NW) {
            float acc[32];
            #pragma unroll
            for (int o = 0; o < 32; ++o) acc[o] = 0.f;
            const float* xp = xb + hh * NW + ww;
            for (int c0 = 0; c0 < NC; c0 += 8) {
                float xv[8];
                #pragma unroll
                for (int j = 0; j < 8; ++j)
                    xv[j] = xp[(size_t)(c0 + j) * HW];
                #pragma unroll
                for (int j = 0; j < 8; ++j) {
                    #pragma unroll
                    for (int o = 0; o < 32; ++o)
                        acc[o] = fmaf(wqkv[(ND + o) * NC + c0 + j], xv[j], acc[o]);
                }
            }
            #pragma unroll
            for (int o = 0; o < 16; ++o) {
                const float kv = acc[o];
                sk[o] = kv > 0.f ? kv + 1.f : __expf(kv);
            }
            #pragma unroll
            for (int o = 0; o < 16; ++o) sv[o] = acc[16 + o];
        } else {
            #pragma unroll
            for (int o = 0; o < 16; ++o) { sk[o] = 0.f; sv[o] = 0.f; }
        }
    }

    const int py = t >> 4;
    const int px = t & 15;
    const int hh = h0 + py;
    const int ww = w0 + px;
    float q[ND];
    {
        float acc[ND];
        #pragma unroll
        for (int o = 0; o < ND; ++o) acc[o] = 0.f;
        const float* xp = xb + hh * NW + ww;
        for (int c0 = 0; c0 < NC; c0 += 8) {
            float xv[8];
            #pragma unroll
            for (int j = 0; j < 8; ++j)
                xv[j] = xp[(size_t)(c0 + j) * HW];
            #pragma unroll
            for (int j = 0; j < 8; ++j) {
                #pragma unroll
                for (int o = 0; o < ND; ++o)
                    acc[o] = fmaf(wqkv[o * NC + c0 + j], xv[j], acc[o]);
            }
        }
        #pragma unroll
        for (int o = 0; o < ND; ++o)
            q[o] = acc[o] > 0.f ? acc[o] + 1.f : __expf(acc[o]);
    }

    __syncthreads();

    float sc[9];
    float ssum = 0.f;
    #pragma unroll
    for (int n = 0; n < 9; ++n) {
        const int np = (py + n / 3) * EW + (px + n % 3);
        const float* sk = &s_k[np * PSTR];
        float s = 0.f;
        #pragma unroll
        for (int d = 0; d < ND; ++d) s = fmaf(q[d], sk[d], s);
        sc[n] = s;
        ssum += s;
    }
    const float inv = 1.f / (ssum + EPSV);

    float ov[ND];
    #pragma unroll
    for (int d = 0; d < ND; ++d) ov[d] = 0.f;
    #pragma unroll
    for (int n = 0; n < 9; ++n) {
        const int np = (py + n / 3) * EW + (px + n % 3);
        const float* sv = &s_v[np * PSTR];
        const float wn = sc[n] * inv;
        #pragma unroll
        for (int d = 0; d < ND; ++d) ov[d] = fmaf(wn, sv[d], ov[d]);
    }

    float* yp = y + (size_t)b * NC * HW + hh * NW + ww;
    #pragma unroll 8
    for (int o = 0; o < NC; ++o) {
        float acc = 0.f;
        #pragma unroll
        for (int d = 0; d < ND; ++d)
            acc = fmaf(wout[o * ND + d], ov[d], acc);
        yp[(size_t)o * HW] = acc;
    }
}

extern "C" void kernel_launch(void* const* d_in, const int* in_sizes, int n_in,
                              void* d_out, int out_size, void* d_ws, size_t ws_size,
                              hipStream_t stream)
{
    const float* x    = (const float*)d_in[0];
    const float* wqkv = (const float*)d_in[1];
    const float* wout = (const float*)d_in[2];
    float* y = (float*)d_out;

    const size_t need = (size_t)NB * HW * NQKV * sizeof(__half);  // ~100.7 MB
    if (ws_size >= need) {
        __half* qkv = (__half*)d_ws;
        const int npix = NB * HW;
        qkv_mfma_kernel<<<npix / 256, 256, 0, stream>>>(x, wqkv, qkv);
        dim3 grid2(NW / 16, NH / 16, NB);
        attn_out_kernel<<<grid2, 256, 0, stream>>>(qkv, wout, y);
    } else {
        dim3 grid(NW / TW, NH / TH, NB);
        na2d_fused_kernel<<<grid, 256, 0, stream>>>(x, wqkv, wout, y);
    }
}

// Round 4
// 226.250 us; speedup vs baseline: 1.9176x; 1.0430x over previous
//
#include <hip/hip_runtime.h>

#define NB 8
#define NC 64
#define NH 256
#define NW 512
#define ND 16
#define HW (NH * NW)          // 131072
#define EPSV 1e-6f
#define EXT 324               // 18x18 extended pixels
#define RSF 52                // LDS record stride in floats (q16|k16|v16|pad4)

typedef __attribute__((ext_vector_type(8))) short bf16x8;
typedef __attribute__((ext_vector_type(4))) float f32x4;

__device__ __forceinline__ short bf_hi(float f) {
    return (short)(__float_as_uint(f) >> 16);           // truncated bf16
}
__device__ __forceinline__ float hi_part(float f) {
    return __uint_as_float(__float_as_uint(f) & 0xFFFF0000u);
}

// ---------------------------------------------------------------------------
// Fully fused: qkv projection (MFMA, bf16 3-term split ~ fp32 accurate) for
// the 18x18 halo tile -> phi -> fp32 records in LDS -> neighborhood attention
// -> output projection. No global intermediate.
// Block = 256 threads (4 waves), tile = 16x16 interior pixels.
// Wave w computes 48 channels x 96 extended pixels (pe = w*96 .. w*96+95).
// ---------------------------------------------------------------------------
__global__ __launch_bounds__(256, 2)
void na2d_fused_mfma(const float* __restrict__ x,
                     const float* __restrict__ wqkv,
                     const float* __restrict__ wout,
                     float* __restrict__ y)
{
    __shared__ float s[EXT * RSF];   // 67392 B

    const int t    = threadIdx.x;
    const int wid  = t >> 6;
    const int lane = t & 63;
    const int lg   = lane >> 4;     // 0..3
    const int lr   = lane & 15;     // 0..15

    // XCD swizzle: 4096 blocks = 8 images x 512 tiles. Round-robin dispatch
    // -> XCD k gets wg in [k*512,(k+1)*512) = exactly one batch image, so
    // halo rows/cols reuse hits that XCD's private L2.
    const int wg = (blockIdx.x & 7) * 512 + (blockIdx.x >> 3);
    const int bx = wg & 31;          // 32 tiles along W
    const int by = (wg >> 5) & 15;   // 16 tiles along H
    const int b  = wg >> 9;          // image
    const int w0 = bx * 16;
    const int h0 = by * 16;

    const float* __restrict__ xb = x + (size_t)b * NC * HW;

    // ---- A fragments: wqkv rows (output channels), hi/lo bf16 split ----
    bf16x8 a_hi[3][2], a_lo[3][2];
    #pragma unroll
    for (int og = 0; og < 3; ++og) {
        const int row = og * 16 + lr;
        #pragma unroll
        for (int ks = 0; ks < 2; ++ks) {
            #pragma unroll
            for (int i = 0; i < 8; ++i) {
                const float wv = wqkv[row * NC + ks * 32 + lg * 8 + i];
                a_hi[og][ks][i] = bf_hi(wv);
                a_lo[og][ks][i] = bf_hi(wv - hi_part(wv));
            }
        }
    }

    f32x4 acc[3][6];
    #pragma unroll
    for (int og = 0; og < 3; ++og) {
        #pragma unroll
        for (int pg = 0; pg < 6; ++pg)
            acc[og][pg] = (f32x4)(0.f);
    }

    const int pb = wid * 96;

    #pragma unroll
    for (int pg = 0; pg < 6; ++pg) {
        const int pe = pb + pg * 16 + lr;     // extended pixel id (may be >= EXT: pad)
        const int ey = pe / 18;
        const int ex = pe - ey * 18;
        int hh = h0 + ey - 1;
        int ww = w0 + ex - 1;
        hh = hh < 0 ? 0 : (hh > NH - 1 ? NH - 1 : hh);   // clamp: safe addresses,
        ww = ww < 0 ? 0 : (ww > NW - 1 ? NW - 1 : ww);   // result zeroed at store
        const float* xp = xb + hh * NW + ww;

        bf16x8 b_hi[2], b_lo[2];
        #pragma unroll
        for (int ks = 0; ks < 2; ++ks) {
            #pragma unroll
            for (int i = 0; i < 8; ++i) {
                const float xv = xp[(size_t)(ks * 32 + lg * 8 + i) * HW];
                b_hi[ks][i] = bf_hi(xv);
                b_lo[ks][i] = bf_hi(xv - hi_part(xv));
            }
        }
        #pragma unroll
        for (int og = 0; og < 3; ++og) {
            #pragma unroll
            for (int ks = 0; ks < 2; ++ks) {
                acc[og][pg] = __builtin_amdgcn_mfma_f32_16x16x32_bf16(a_hi[og][ks], b_hi[ks], acc[og][pg], 0, 0, 0);
                acc[og][pg] = __builtin_amdgcn_mfma_f32_16x16x32_bf16(a_lo[og][ks], b_hi[ks], acc[og][pg], 0, 0, 0);
                acc[og][pg] = __builtin_amdgcn_mfma_f32_16x16x32_bf16(a_hi[og][ks], b_lo[ks], acc[og][pg], 0, 0, 0);
            }
        }
    }

    // ---- phi on q,k; zero OOB; store records to LDS ----
    // D layout: channel = og*16 + lg*4 + i, pixel = pe(pg, lr).
    #pragma unroll
    for (int pg = 0; pg < 6; ++pg) {
        const int pe = pb + pg * 16 + lr;
        if (pe < EXT) {
            const int ey = pe / 18;
            const int ex = pe - ey * 18;
            const int hh = h0 + ey - 1;
            const int ww = w0 + ex - 1;
            const bool valid = (unsigned)hh < NH && (unsigned)ww < NW;
            #pragma unroll
            for (int og = 0; og < 3; ++og) {
                f32x4 v = acc[og][pg];
                if (og < 2) {                     // phi = elu + 1 on q and k
                    #pragma unroll
                    for (int i = 0; i < 4; ++i)
                        v[i] = v[i] > 0.f ? v[i] + 1.f : __expf(v[i]);
                }
                if (!valid) v = (f32x4)(0.f);     // zero-pad AFTER phi
                *reinterpret_cast<f32x4*>(&s[pe * RSF + og * 16 + lg * 4]) = v;
            }
        }
    }
    __syncthreads();

    // ---- attention + output projection (1 thread per interior pixel) ----
    const int px = t & 15, py = t >> 4;

    f32x4 qv[4];
    {
        const int r = (py + 1) * 18 + (px + 1);
        #pragma unroll
        for (int i = 0; i < 4; ++i)
            qv[i] = *reinterpret_cast<const f32x4*>(&s[r * RSF + i * 4]);
    }
    const float* q = reinterpret_cast<const float*>(qv);

    float sc[9];
    float ssum = 0.f;
    #pragma unroll
    for (int n = 0; n < 9; ++n) {
        const int r = (py + n / 3) * 18 + (px + n % 3);
        f32x4 k0 = *reinterpret_cast<const f32x4*>(&s[r * RSF + 16]);
        f32x4 k1 = *reinterpret_cast<const f32x4*>(&s[r * RSF + 20]);
        f32x4 k2 = *reinterpret_cast<const f32x4*>(&s[r * RSF + 24]);
        f32x4 k3 = *reinterpret_cast<const f32x4*>(&s[r * RSF + 28]);
        float sv = 0.f;
        #pragma unroll
        for (int i = 0; i < 4; ++i) sv = fmaf(q[i], k0[i], sv);
        #pragma unroll
        for (int i = 0; i < 4; ++i) sv = fmaf(q[4 + i], k1[i], sv);
        #pragma unroll
        for (int i = 0; i < 4; ++i) sv = fmaf(q[8 + i], k2[i], sv);
        #pragma unroll
        for (int i = 0; i < 4; ++i) sv = fmaf(q[12 + i], k3[i], sv);
        sc[n] = sv;
        ssum += sv;
    }
    const float inv = 1.f / (ssum + EPSV);

    float ov[ND];
    #pragma unroll
    for (int d = 0; d < ND; ++d) ov[d] = 0.f;
    #pragma unroll
    for (int n = 0; n < 9; ++n) {
        const int r = (py + n / 3) * 18 + (px + n % 3);
        const float wn = sc[n] * inv;
        f32x4 v0 = *reinterpret_cast<const f32x4*>(&s[r * RSF + 32]);
        f32x4 v1 = *reinterpret_cast<const f32x4*>(&s[r * RSF + 36]);
        f32x4 v2 = *reinterpret_cast<const f32x4*>(&s[r * RSF + 40]);
        f32x4 v3 = *reinterpret_cast<const f32x4*>(&s[r * RSF + 44]);
        #pragma unroll
        for (int i = 0; i < 4; ++i) ov[i]      = fmaf(wn, v0[i], ov[i]);
        #pragma unroll
        for (int i = 0; i < 4; ++i) ov[4 + i]  = fmaf(wn, v1[i], ov[4 + i]);
        #pragma unroll
        for (int i = 0; i < 4; ++i) ov[8 + i]  = fmaf(wn, v2[i], ov[8 + i]);
        #pragma unroll
        for (int i = 0; i < 4; ++i) ov[12 + i] = fmaf(wn, v3[i], ov[12 + i]);
    }

    // output projection 16 -> 64 (wout rows via scalar cache, wave-uniform)
    const int h = h0 + py, w = w0 + px;
    float* yp = y + (size_t)b * NC * HW + h * NW + w;
    #pragma unroll 8
    for (int o = 0; o < NC; ++o) {
        float a = 0.f;
        #pragma unroll
        for (int d = 0; d < ND; ++d)
            a = fmaf(wout[o * ND + d], ov[d], a);
        yp[(size_t)o * HW] = a;
    }
}

extern "C" void kernel_launch(void* const* d_in, const int* in_sizes, int n_in,
                              void* d_out, int out_size, void* d_ws, size_t ws_size,
                              hipStream_t stream)
{
    const float* x    = (const float*)d_in[0];
    const float* wqkv = (const float*)d_in[1];
    const float* wout = (const float*)d_in[2];
    float* y = (float*)d_out;

    const int nblocks = (NW / 16) * (NH / 16) * NB;   // 4096
    na2d_fused_mfma<<<nblocks, 256, 0, stream>>>(x, wqkv, wout, y);
}

// Round 5
// 209.557 us; speedup vs baseline: 2.0703x; 1.0797x over previous
//
#include <hip/hip_runtime.h>
#include <hip/hip_fp16.h>
#include <hip/hip_bf16.h>

#define NB 8
#define NC 64
#define NH 256
#define NW 512
#define ND 16
#define HW (NH * NW)          // 131072
#define EPSV 1e-6f
#define EXT 324               // 18x18 extended pixels
#define RSH 56                // LDS record stride in halves (112 B, 16B-multiple)

typedef __attribute__((ext_vector_type(8))) short bf16x8;
typedef __attribute__((ext_vector_type(4))) float f32x4;

__device__ __forceinline__ unsigned pack_bf16rn(float aa, float bb) {
    union { __hip_bfloat162 h2; unsigned u; } c;
    c.h2 = __float22bfloat162_rn(float2{aa, bb});
    return c.u;
}
__device__ __forceinline__ float hi_part(float f) {
    return __uint_as_float(__float_as_uint(f) & 0xFFFF0000u);
}
__device__ __forceinline__ unsigned pack_hi2(float aa, float bb) {
    return (__float_as_uint(bb) & 0xFFFF0000u) | (__float_as_uint(aa) >> 16);
}
__device__ __forceinline__ void unpack16(const __half* sp, float* f) {
    const uint4 u0 = *reinterpret_cast<const uint4*>(sp);
    const uint4 u1 = *reinterpret_cast<const uint4*>(sp + 8);
    union { unsigned u; __half2 h; } c;
    c.u = u0.x; *reinterpret_cast<float2*>(f + 0)  = __half22float2(c.h);
    c.u = u0.y; *reinterpret_cast<float2*>(f + 2)  = __half22float2(c.h);
    c.u = u0.z; *reinterpret_cast<float2*>(f + 4)  = __half22float2(c.h);
    c.u = u0.w; *reinterpret_cast<float2*>(f + 6)  = __half22float2(c.h);
    c.u = u1.x; *reinterpret_cast<float2*>(f + 8)  = __half22float2(c.h);
    c.u = u1.y; *reinterpret_cast<float2*>(f + 10) = __half22float2(c.h);
    c.u = u1.z; *reinterpret_cast<float2*>(f + 12) = __half22float2(c.h);
    c.u = u1.w; *reinterpret_cast<float2*>(f + 14) = __half22float2(c.h);
}

// ---------------------------------------------------------------------------
// Fully fused NA2D. Block = 512 threads (8 waves), tile = 16x16 interior.
// Projection: wave w computes 48 channels x 48 extended pixels via MFMA
// (W single rounded-bf16, x exact hi/lo 2-term). Records stored fp16 in LDS
// (36.3 KB) -> 2 blocks/CU = 16 waves/CU.
// Attention: wave-pair handles 64 pixels; channel-half split by wave parity.
// ---------------------------------------------------------------------------
__global__ __launch_bounds__(512, 4)
void na2d_fused_v5(const float* __restrict__ x,
                   const float* __restrict__ wqkv,
                   const float* __restrict__ wout,
                   float* __restrict__ y)
{
    __shared__ __align__(16) __half s[EXT * RSH];   // 36288 B

    const int t    = threadIdx.x;
    const int wid  = t >> 6;
    const int lane = t & 63;
    const int lg   = lane >> 4;     // 0..3
    const int lr   = lane & 15;     // 0..15

    // XCD swizzle: 4096 blocks = 8 images x 512 tiles; each XCD owns 1 image.
    const int wg = (blockIdx.x & 7) * 512 + (blockIdx.x >> 3);
    const int bx = wg & 31;
    const int by = (wg >> 5) & 15;
    const int b  = wg >> 9;
    const int w0 = bx * 16;
    const int h0 = by * 16;

    const float* __restrict__ xb = x + (size_t)b * NC * HW;

    // ---- A fragments: wqkv rows, single rounded bf16 (24 VGPR) ----
    bf16x8 a[3][2];
    #pragma unroll
    for (int og = 0; og < 3; ++og) {
        const int row = og * 16 + lr;
        #pragma unroll
        for (int ks = 0; ks < 2; ++ks) {
            union { bf16x8 v; unsigned u[4]; } r;
            #pragma unroll
            for (int i = 0; i < 4; ++i)
                r.u[i] = pack_bf16rn(wqkv[row * NC + ks * 32 + lg * 8 + 2 * i],
                                     wqkv[row * NC + ks * 32 + lg * 8 + 2 * i + 1]);
            a[og][ks] = r.v;
        }
    }

    f32x4 acc[3][3];
    #pragma unroll
    for (int og = 0; og < 3; ++og)
        #pragma unroll
        for (int pg = 0; pg < 3; ++pg)
            acc[og][pg] = (f32x4)(0.f);

    const int pb = wid * 48;    // wave's first extended pixel (wave 7: all pad)

    #pragma unroll
    for (int pg = 0; pg < 3; ++pg) {
        if (pb + pg * 16 < EXT) {                    // wave-uniform skip
            const int pe = pb + pg * 16 + lr;
            const int ey = pe / 18;
            const int ex = pe - ey * 18;
            int hh = h0 + ey - 1;
            int ww = w0 + ex - 1;
            hh = hh < 0 ? 0 : (hh > NH - 1 ? NH - 1 : hh);  // clamp (zeroed later)
            ww = ww < 0 ? 0 : (ww > NW - 1 ? NW - 1 : ww);
            const float* xp = xb + hh * NW + ww;

            float xv[16];
            #pragma unroll
            for (int j = 0; j < 16; ++j)
                xv[j] = xp[(size_t)((j >> 3) * 32 + lg * 8 + (j & 7)) * HW];

            union { bf16x8 v; unsigned u[4]; } bh[2], bl[2];
            #pragma unroll
            for (int ks = 0; ks < 2; ++ks)
                #pragma unroll
                for (int i = 0; i < 4; ++i) {
                    const float f0 = xv[ks * 8 + 2 * i];
                    const float f1 = xv[ks * 8 + 2 * i + 1];
                    bh[ks].u[i] = pack_hi2(f0, f1);
                    bl[ks].u[i] = pack_hi2(f0 - hi_part(f0), f1 - hi_part(f1));
                }
            #pragma unroll
            for (int og = 0; og < 3; ++og) {
                #pragma unroll
                for (int ks = 0; ks < 2; ++ks) {
                    acc[og][pg] = __builtin_amdgcn_mfma_f32_16x16x32_bf16(a[og][ks], bh[ks].v, acc[og][pg], 0, 0, 0);
                    acc[og][pg] = __builtin_amdgcn_mfma_f32_16x16x32_bf16(a[og][ks], bl[ks].v, acc[og][pg], 0, 0, 0);
                }
            }
        }
    }

    // ---- phi on q,k; zero OOB; pack fp16 -> LDS records ----
    #pragma unroll
    for (int pg = 0; pg < 3; ++pg) {
        const int pe = pb + pg * 16 + lr;
        if (pe < EXT) {
            const int ey = pe / 18;
            const int ex = pe - ey * 18;
            const int hh = h0 + ey - 1;
            const int ww = w0 + ex - 1;
            const bool valid = (unsigned)hh < NH && (unsigned)ww < NW;
            #pragma unroll
            for (int og = 0; og < 3; ++og) {
                f32x4 v = acc[og][pg];
                if (og < 2) {                        // phi = elu + 1 on q,k
                    #pragma unroll
                    for (int i = 0; i < 4; ++i)
                        v[i] = v[i] > 0.f ? v[i] + 1.f : __expf(v[i]);
                }
                if (!valid) v = (f32x4)(0.f);        // zero-pad AFTER phi
                union { uint2 d; struct { __half2 a2, b2; } h; } pk;
                pk.h.a2 = __floats2half2_rn(v[0], v[1]);
                pk.h.b2 = __floats2half2_rn(v[2], v[3]);
                *reinterpret_cast<uint2*>(&s[pe * RSH + og * 16 + lg * 4]) = pk.d;
            }
        }
    }
    __syncthreads();

    // ---- attention + out-projection ----
    // wave-pair (2w, 2w+1) both handle pixels p = w*64 + lane; channel half
    // by wave parity (wave-uniform -> wout via s_load).
    const int chalf = __builtin_amdgcn_readfirstlane(wid & 1);
    const int p  = (wid >> 1) * 64 + lane;
    const int py = p >> 4, px = p & 15;

    float q[ND];
    unpack16(&s[((py + 1) * 18 + (px + 1)) * RSH], q);

    float sc[9];
    float ssum = 0.f;
    #pragma unroll
    for (int n = 0; n < 9; ++n) {
        const int r = (py + n / 3) * 18 + (px + n % 3);
        float kf[ND];
        unpack16(&s[r * RSH + 16], kf);
        float sv = 0.f;
        #pragma unroll
        for (int d = 0; d < ND; ++d) sv = fmaf(q[d], kf[d], sv);
        sc[n] = sv;
        ssum += sv;
    }
    const float inv = 1.f / (ssum + EPSV);

    float ov[ND];
    #pragma unroll
    for (int d = 0; d < ND; ++d) ov[d] = 0.f;
    #pragma unroll
    for (int n = 0; n < 9; ++n) {
        const int r = (py + n / 3) * 18 + (px + n % 3);
        float vf[ND];
        unpack16(&s[r * RSH + 32], vf);
        const float wn = sc[n] * inv;
        #pragma unroll
        for (int d = 0; d < ND; ++d) ov[d] = fmaf(wn, vf[d], ov[d]);
    }

    // out-projection: 32 channels (chalf picks which half)
    const int h = h0 + py, w = w0 + px;
    float* yp = y + (size_t)b * NC * HW + (size_t)(chalf * 32) * HW + h * NW + w;
    const float* wo = wout + (chalf * 32) * ND;
    #pragma unroll 8
    for (int o = 0; o < 32; ++o) {
        float a2 = 0.f;
        #pragma unroll
        for (int d = 0; d < ND; ++d)
            a2 = fmaf(wo[o * ND + d], ov[d], a2);
        yp[(size_t)o * HW] = a2;
    }
}

extern "C" void kernel_launch(void* const* d_in, const int* in_sizes, int n_in,
                              void* d_out, int out_size, void* d_ws, size_t ws_size,
                              hipStream_t stream)
{
    const float* x    = (const float*)d_in[0];
    const float* wqkv = (const float*)d_in[1];
    const float* wout = (const float*)d_in[2];
    float* y = (float*)d_out;

    const int nblocks = (NW / 16) * (NH / 16) * NB;   // 4096
    na2d_fused_v5<<<nblocks, 512, 0, stream>>>(x, wqkv, wout, y);
}